// Round 1
// 147.421 us; speedup vs baseline: 1.0185x; 1.0185x over previous
//
#include <hip/hip_runtime.h>

// ShiftVarConv2D: out[n,m,y,x] = sum_{di,dj} coded[n,y+di-1,x+dj-1] *
//                 W[(y%8)*8+(x%8), m, di*3+dj] + bias[g*16+m]
// N=128, H=128, SUB=16 out channels, 3x3 window, weights vary with (y%8,x%8).

#define H 128
#define N_BATCH 128
#define SUB 16

// Wt layout: [b1][m][80] where the 80 floats are, for h in {0,1}:
//   offset h*40 + i*4 + jj  = W[b2=4h+jj, m, tap i]   (tap-major -> float4/tap)
//   offset h*40 + 36 + jj   = bias[b2=4h+jj, m]
// All float4-aligned so the main kernel reads weights as ds_read_b128.
__global__ void wprep_kernel(const float* __restrict__ w,
                             const float* __restrict__ bias,
                             float* __restrict__ Wt) {
    int t = blockIdx.x * blockDim.x + threadIdx.x;   // 0..1023
    if (t >= 8 * 16 * 8) return;
    int b1 = t >> 7;          // 0..7
    int m  = (t >> 3) & 15;   // 0..15
    int j  = t & 7;           // 0..7  (= b2)
    int h  = j >> 2;          // 0..1
    int jj = j & 3;           // 0..3
    int oc = (b1 * 8 + j) * 16 + m;
    float* dst = Wt + (b1 * 16 + m) * 80 + h * 40;
#pragma unroll
    for (int i = 0; i < 9; ++i) dst[i * 4 + jj] = w[oc * 9 + i];
    dst[36 + jj] = bias[oc];
}

// grid = 4096 blocks (n:128, b1:8, rh:2, mh:2), XCD-swizzled: low 3 bits = n&7.
// block = 256 threads: c = t&31 -> x0 = 4c (one float4 of output per m),
// r8 = t>>5 -> row y = b1 + 64*rh + 8*r8. Stores are wave-contiguous:
// 32 lanes x 16B = 512B per half-wave row segment.
// Halo columns (x0-1, x0+4) come from neighbor lanes via __shfl, not global
// loads; c==0 / c==31 are exactly the zero-pad positions so they get cndmask'd.
__global__ __launch_bounds__(256, 8) void shiftconv_kernel(
        const float* __restrict__ x,
        const float* __restrict__ Wt,
        float* __restrict__ out) {
    int bid = blockIdx.x;
    int nlo = bid & 7;            // XCD-swizzle: same n -> same XCD
    int q   = bid >> 3;
    int mh  = q & 1;
    int rh  = (q >> 1) & 1;
    int b1  = (q >> 2) & 7;
    int n   = ((q >> 5) << 3) | nlo;

    // Stage this block's weights (8 m x 80 floats = 2560 B) into LDS.
    __shared__ float ws[8 * 80];
    {
        int t = threadIdx.x;
        if (t < 160)
            ((float4*)ws)[t] = ((const float4*)(Wt + (b1 * 16 + mh * 8) * 80))[t];
    }

    int c  = threadIdx.x & 31;    // x0 = 4c
    int r8 = threadIdx.x >> 5;    // 0..7
    int y  = b1 + (rh << 6) + (r8 << 3);
    int x0 = c << 2;
    int h  = c & 1;               // x0 % 8 == 4h -> b2 = 4h + jj

    const float* xn = x + (size_t)n * (H * H);

    // in[dy][k] = coded[n, y+dy-1, x0+k-1] (zero padded), k in [0,6)
    // One aligned float4 load per row; halo from neighbor lanes via shuffle.
    float in[3][6];
#pragma unroll
    for (int dy = 0; dy < 3; ++dy) {
        int ry = y + dy - 1;
        float4 a = make_float4(0.0f, 0.0f, 0.0f, 0.0f);
        if (ry >= 0 && ry < H) a = *(const float4*)(xn + ry * H + x0);
        in[dy][1] = a.x; in[dy][2] = a.y; in[dy][3] = a.z; in[dy][4] = a.w;
        float left  = __shfl_up(a.w, 1);    // lane c-1's a.w == row[x0-1]
        float right = __shfl_down(a.x, 1);  // lane c+1's a.x == row[x0+4]
        in[dy][0] = (c == 0)  ? 0.0f : left;    // x0-1 < 0 pad
        in[dy][5] = (c == 31) ? 0.0f : right;   // x0+4 >= H pad
    }

    __syncthreads();

    float* outbase = out + ((size_t)(n * SUB + mh * 8)) * (H * H) + y * H + x0;

#pragma unroll
    for (int mi = 0; mi < 8; ++mi) {
        const float4* wp = (const float4*)(ws + mi * 80 + h * 40);
        float4 b4 = wp[9];                    // bias for jj=0..3
        float acc[4] = {b4.x, b4.y, b4.z, b4.w};
#pragma unroll
        for (int dy = 0; dy < 3; ++dy) {
#pragma unroll
            for (int dj = 0; dj < 3; ++dj) {
                float4 w4 = wp[dy * 3 + dj];  // one ds_read_b128 = 4 weights
                acc[0] = fmaf(in[dy][dj + 0], w4.x, acc[0]);
                acc[1] = fmaf(in[dy][dj + 1], w4.y, acc[1]);
                acc[2] = fmaf(in[dy][dj + 2], w4.z, acc[2]);
                acc[3] = fmaf(in[dy][dj + 3], w4.w, acc[3]);
            }
        }
        *(float4*)(outbase + (size_t)mi * (H * H)) =
            make_float4(acc[0], acc[1], acc[2], acc[3]);
    }
}

extern "C" void kernel_launch(void* const* d_in, const int* in_sizes, int n_in,
                              void* d_out, int out_size, void* d_ws, size_t ws_size,
                              hipStream_t stream) {
    const float* coded  = (const float*)d_in[0];
    const float* weight = (const float*)d_in[1];
    const float* bias   = (const float*)d_in[2];
    float* out = (float*)d_out;
    float* Wt  = (float*)d_ws;   // 8*16*80*4 = 40960 bytes

    wprep_kernel<<<4, 256, 0, stream>>>(weight, bias, Wt);
    shiftconv_kernel<<<N_BATCH * 8 * 2 * 2, 256, 0, stream>>>(coded, Wt, out);
}

// Round 2
// 146.089 us; speedup vs baseline: 1.0278x; 1.0091x over previous
//
#include <hip/hip_runtime.h>

// ShiftVarConv2D: out[n,m,y,x] = sum_{di,dj} coded[n,y+di-1,x+dj-1] *
//                 W[(y%8)*8+(x%8), m, di*3+dj] + bias[g*16+m]
// N=128, H=128, SUB=16 out channels, 3x3 window, weights vary with (y%8,x%8).
//
// This version: single kernel (weight transpose folded into per-block LDS
// staging; d_ws unused), and each thread computes TWO output rows (y, y+64 —
// same y%8, so identical weights), halving total LDS read instructions.

#define H 128
#define N_BATCH 128
#define SUB 16

// grid = 2048 blocks (n:128, b1:8, mh:2), XCD-swizzled: low 3 bits = n&7.
// block = 256 threads: c = t&31 -> x0 = 4c, r = t>>5 -> rows y0 = b1+8r and
// y1 = y0+64. Per mi (8 m-planes): 10 ds_read_b128 serve 8 output pixels
// (2 rows x float4). Stores are wave-contiguous 512B row segments.
__global__ __launch_bounds__(256, 4) void shiftconv_kernel(
        const float* __restrict__ x,
        const float* __restrict__ w,
        const float* __restrict__ bias,
        float* __restrict__ out) {
    int bid = blockIdx.x;
    int nlo = bid & 7;            // XCD-swizzle: same n -> same XCD
    int q   = bid >> 3;
    int mh  = q & 1;
    int b1  = (q >> 1) & 7;
    int n   = ((q >> 4) << 3) | nlo;

    // Stage + transpose this block's weights (8 m x 80 floats = 2560 B).
    // ws[mi*80 + h*40 + i*4 + jj] = w[oc*9 + i],  oc = (b1*8+4h+jj)*16 + m
    // ws[mi*80 + h*40 + 36 + jj]  = bias[oc]      (float4-aligned per tap)
    __shared__ float ws[8 * 80];
    {
        int t = threadIdx.x;
        if (t < 64) {
            int mi = t >> 3;
            int h  = (t >> 2) & 1;
            int jj = t & 3;
            int oc = (b1 * 8 + 4 * h + jj) * 16 + (mh * 8 + mi);
            float* dst = ws + mi * 80 + h * 40;
            const float* src = w + oc * 9;
#pragma unroll
            for (int i = 0; i < 9; ++i) dst[i * 4 + jj] = src[i];
            dst[36 + jj] = bias[oc];
        }
    }

    int c  = threadIdx.x & 31;    // x0 = 4c
    int r  = threadIdx.x >> 5;    // 0..7
    int x0 = c << 2;
    int h  = c & 1;               // x0 % 8 == 4h -> b2 = 4h + jj
    int y0 = b1 + (r << 3);       // row group 0; group 1 is y0 + 64

    const float* xn = x + (size_t)n * (H * H);

    // in[g][dy][k] = coded[n, yg+dy-1, x0+k-1] (zero padded), k in [0,6)
    // One aligned float4 load per row; halo from neighbor lanes via shuffle.
    float in[2][3][6];
#pragma unroll
    for (int g = 0; g < 2; ++g) {
        int yg = y0 + (g << 6);
#pragma unroll
        for (int dy = 0; dy < 3; ++dy) {
            int ry = yg + dy - 1;
            float4 a = make_float4(0.0f, 0.0f, 0.0f, 0.0f);
            if (ry >= 0 && ry < H) a = *(const float4*)(xn + ry * H + x0);
            in[g][dy][1] = a.x; in[g][dy][2] = a.y;
            in[g][dy][3] = a.z; in[g][dy][4] = a.w;
            float left  = __shfl_up(a.w, 1);    // lane c-1's a.w == row[x0-1]
            float right = __shfl_down(a.x, 1);  // lane c+1's a.x == row[x0+4]
            in[g][dy][0] = (c == 0)  ? 0.0f : left;    // x0-1 < 0 pad
            in[g][dy][5] = (c == 31) ? 0.0f : right;   // x0+4 >= H pad
        }
    }

    __syncthreads();

    float* ob = out + ((size_t)(n * SUB + mh * 8)) * (H * H) + y0 * H + x0;

#pragma unroll
    for (int mi = 0; mi < 8; ++mi) {
        const float4* wp = (const float4*)(ws + mi * 80 + h * 40);
        float4 b4 = wp[9];                    // bias for jj=0..3
        float a0[4] = {b4.x, b4.y, b4.z, b4.w};
        float a1[4] = {b4.x, b4.y, b4.z, b4.w};
#pragma unroll
        for (int dy = 0; dy < 3; ++dy) {
#pragma unroll
            for (int dj = 0; dj < 3; ++dj) {
                float4 w4 = wp[dy * 3 + dj];  // one ds_read_b128 = 4 weights
                a0[0] = fmaf(in[0][dy][dj + 0], w4.x, a0[0]);
                a0[1] = fmaf(in[0][dy][dj + 1], w4.y, a0[1]);
                a0[2] = fmaf(in[0][dy][dj + 2], w4.z, a0[2]);
                a0[3] = fmaf(in[0][dy][dj + 3], w4.w, a0[3]);
                a1[0] = fmaf(in[1][dy][dj + 0], w4.x, a1[0]);
                a1[1] = fmaf(in[1][dy][dj + 1], w4.y, a1[1]);
                a1[2] = fmaf(in[1][dy][dj + 2], w4.z, a1[2]);
                a1[3] = fmaf(in[1][dy][dj + 3], w4.w, a1[3]);
            }
        }
        float* p = ob + (size_t)mi * (H * H);
        *(float4*)(p)          = make_float4(a0[0], a0[1], a0[2], a0[3]);
        *(float4*)(p + 64 * H) = make_float4(a1[0], a1[1], a1[2], a1[3]);
    }
}

extern "C" void kernel_launch(void* const* d_in, const int* in_sizes, int n_in,
                              void* d_out, int out_size, void* d_ws, size_t ws_size,
                              hipStream_t stream) {
    const float* coded  = (const float*)d_in[0];
    const float* weight = (const float*)d_in[1];
    const float* bias   = (const float*)d_in[2];
    float* out = (float*)d_out;

    shiftconv_kernel<<<N_BATCH * 8 * 2, 256, 0, stream>>>(coded, weight, bias, out);
}